// Round 1
// 349.375 us; speedup vs baseline: 1.1130x; 1.1130x over previous
//
#include <hip/hip_runtime.h>
#include <math.h>

#define WE 300
#define DEp 256
#define VV 50000
#define DDim 100000
#define BB 4096
#define NGc 10
#define RVT_STRIDE 304   // padded row stride (floats) for rvT, 16B-aligned

__device__ __forceinline__ float wave_reduce(float v) {
    #pragma unroll
    for (int o = 32; o > 0; o >>= 1) v += __shfl_down(v, o, 64);
    return v;
}

// log(sigmoid(x)), numerically stable
__device__ __forceinline__ float logsigf(float x) {
    return (x >= 0.f) ? -log1pf(expf(-x)) : x - log1pf(expf(x));
}

__global__ void k_init(double* p, int n) {
    int i = blockIdx.x * blockDim.x + threadIdx.x;
    if (i < n) p[i] = 0.0;
}

// ---- rd transpose: 256 x 100000 -> 100000 x 256, fused sum(rd*rd). ----
// One block per 64-column tile, covering ALL 256 rows. Each block's output
// region is a single contiguous 64 KB span -> perfectly sequential stores.
// LDS: 64KB of float4 with XOR swizzle A = nl*64 + (m4 ^ nl):
//   phase-1 b128 writes 2-way (free), phase-2 b128 reads linear-equivalent.
__global__ __launch_bounds__(256) void k_trd(const float* __restrict__ in,
                                             float* __restrict__ out,
                                             double* __restrict__ reg_acc) {
    __shared__ float4 tile[64 * 64];
    const int N = DDim;
    int n0 = blockIdx.x * 64;
    int t = threadIdx.x;
    float ss = 0.f;
    #pragma unroll
    for (int i = 0; i < 4; ++i) {
        int flat = i * 256 + t;
        int qn = flat & 15;        // n-quad within tile (0..15)
        int qm = flat >> 4;        // m-quad (0..63)
        int n = n0 + qn * 4;
        float4 v0, v1, v2, v3;
        if (n < N) {               // N%4==0 so n<N => n+3<N
            const float* p = in + (size_t)(qm * 4) * N + n;
            v0 = *(const float4*)(p);
            v1 = *(const float4*)(p + N);
            v2 = *(const float4*)(p + 2 * (size_t)N);
            v3 = *(const float4*)(p + 3 * (size_t)N);
        } else {
            v0 = v1 = v2 = v3 = make_float4(0.f, 0.f, 0.f, 0.f);
        }
        ss += v0.x * v0.x + v0.y * v0.y + v0.z * v0.z + v0.w * v0.w;
        ss += v1.x * v1.x + v1.y * v1.y + v1.z * v1.z + v1.w * v1.w;
        ss += v2.x * v2.x + v2.y * v2.y + v2.z * v2.z + v2.w * v2.w;
        ss += v3.x * v3.x + v3.y * v3.y + v3.z * v3.z + v3.w * v3.w;
        int nl0 = qn * 4;
        tile[(nl0 + 0) * 64 + (qm ^ (nl0 + 0))] = make_float4(v0.x, v1.x, v2.x, v3.x);
        tile[(nl0 + 1) * 64 + (qm ^ (nl0 + 1))] = make_float4(v0.y, v1.y, v2.y, v3.y);
        tile[(nl0 + 2) * 64 + (qm ^ (nl0 + 2))] = make_float4(v0.z, v1.z, v2.z, v3.z);
        tile[(nl0 + 3) * 64 + (qm ^ (nl0 + 3))] = make_float4(v0.w, v1.w, v2.w, v3.w);
    }
    __syncthreads();
    size_t base = (size_t)n0 * DEp;   // floats
    #pragma unroll
    for (int i = 0; i < 16; ++i) {
        int j = i * 256 + t;          // float4 index within block's out region
        int nl = j >> 6;              // wave-uniform
        if (n0 + nl < N)
            *(float4*)(out + base + (size_t)j * 4) = tile[nl * 64 + ((j & 63) ^ nl)];
    }
    float r = wave_reduce(ss);
    __shared__ float part[4];
    int lane = t & 63, wv = t >> 6;
    if (lane == 0) part[wv] = r;
    __syncthreads();
    if (t == 0)
        atomicAdd(reg_acc, (double)(part[0] + part[1] + part[2] + part[3]));
}

// ---- rv transpose: 300 x 50000 -> 50000 x 304 (padded rows). ----
// Same structure; block output region = 64 rows * 1216B, contiguous.
// LDS 64x80 float4 (80KB, 2 blocks/CU), swizzle m4 ^ (nl>>2) (m4|15 <= 79).
__global__ __launch_bounds__(256) void k_trv(const float* __restrict__ in,
                                             float* __restrict__ out) {
    __shared__ float4 tile[64 * 80];
    const int N = VV;
    int n0 = blockIdx.x * 64;
    int t = threadIdx.x;
    #pragma unroll
    for (int i = 0; i < 5; ++i) {
        int flat = i * 256 + t;
        if (flat < 1200) {            // 75 m-quads * 16 n-quads
            int qn = flat & 15;
            int qm = flat >> 4;       // 0..74
            int n = n0 + qn * 4;
            float4 v0, v1, v2, v3;
            if (n < N) {
                const float* p = in + (size_t)(qm * 4) * N + n;
                v0 = *(const float4*)(p);
                v1 = *(const float4*)(p + N);
                v2 = *(const float4*)(p + 2 * (size_t)N);
                v3 = *(const float4*)(p + 3 * (size_t)N);
            } else {
                v0 = v1 = v2 = v3 = make_float4(0.f, 0.f, 0.f, 0.f);
            }
            int sw = qm ^ qn;         // swz = nl>>2 = qn for k2 in 0..3
            tile[(qn * 4 + 0) * 80 + sw] = make_float4(v0.x, v1.x, v2.x, v3.x);
            tile[(qn * 4 + 1) * 80 + sw] = make_float4(v0.y, v1.y, v2.y, v3.y);
            tile[(qn * 4 + 2) * 80 + sw] = make_float4(v0.z, v1.z, v2.z, v3.z);
            tile[(qn * 4 + 3) * 80 + sw] = make_float4(v0.w, v1.w, v2.w, v3.w);
        }
    }
    __syncthreads();
    size_t base = (size_t)n0 * (RVT_STRIDE / 4);   // float4 units
    float4* out4 = (float4*)out;
    for (int i = 0; i < 19; ++i) {    // 64 * 76 = 4864 float4 per block
        int j = i * 256 + t;
        int nl = j / 76;
        int m4 = j - nl * 76;         // 75 == pad column: writes LDS junk, never read
        if (n0 + nl < N)
            out4[base + j] = tile[nl * 80 + (m4 ^ (nl >> 2))];
    }
}

// ---- Coalesced path (uses rvT / rdT) ----

// One block per b (320 threads, 300 active): gather g column from rvT, normalize.
__global__ __launch_bounds__(320) void k_gather2(const float* __restrict__ rvT,
                                                 const int* __restrict__ wid,
                                                 float* __restrict__ normed) {
    int b = blockIdx.x;
    int tid = threadIdx.x;
    __shared__ int ids[NGc];
    __shared__ float wpart[5];
    __shared__ float s_inv;
    if (tid < NGc) ids[tid] = wid[b * NGc + tid];
    __syncthreads();
    float g = 0.f;
    if (tid < WE) {
        #pragma unroll
        for (int ng = 0; ng < NGc; ++ng) g += rvT[(size_t)ids[ng] * RVT_STRIDE + tid];
        g *= 0.1f;
    }
    float r = wave_reduce(g * g);
    int lane = tid & 63, wv = tid >> 6;
    if (lane == 0) wpart[wv] = r;
    __syncthreads();
    if (tid == 0) {
        float s = wpart[0] + wpart[1] + wpart[2] + wpart[3] + wpart[4];
        s_inv = 1.0f / sqrtf(s);
    }
    __syncthreads();
    if (tid < WE) normed[(size_t)b * WE + tid] = g * s_inv;
}

// One block per b: t column, dot with 1 doc + 10 neg rdT rows (coalesced), log terms.
__global__ __launch_bounds__(256) void k_loss2(const float* __restrict__ tpre,
                                               const float* __restrict__ meanf,
                                               const float* __restrict__ scalef,
                                               const float* __restrict__ beta,
                                               const float* __restrict__ rdT,
                                               const int* __restrict__ doc_ids,
                                               const int* __restrict__ neg_ids,
                                               double* __restrict__ acc) {
    int b = blockIdx.x;
    int de = threadIdx.x;
    float t = tpre[(size_t)b * DEp + de];
    float tv = (t - meanf[de]) * scalef[de] + beta[de];
    tv = fminf(1.f, fmaxf(-1.f, tv));
    __shared__ int ids[11];
    if (de == 0) ids[0] = doc_ids[b];
    if (de >= 1 && de < 11) ids[de] = neg_ids[b * NGc + de - 1];
    __syncthreads();
    float prod[11];
    #pragma unroll
    for (int j = 0; j < 11; ++j) prod[j] = tv * rdT[(size_t)ids[j] * DEp + de];
    __shared__ float part[11][4];
    int lane = de & 63, wv = de >> 6;
    #pragma unroll
    for (int j = 0; j < 11; ++j) {
        float r = wave_reduce(prod[j]);
        if (lane == 0) part[j][wv] = r;
    }
    __syncthreads();
    if (de == 0) {
        float x0 = part[0][0] + part[0][1] + part[0][2] + part[0][3];
        float total = 10.f * fminf(logsigf(x0), -1.0005003e-3f);  // Z*log(min(sig,0.999))
        #pragma unroll
        for (int j = 1; j < 11; ++j) {
            float xj = part[j][0] + part[j][1] + part[j][2] + part[j][3];
            total += fmaxf(logsigf(-xj), -4.6051702f);            // log(max(1-sig,0.01))
        }
        atomicAdd(acc, (double)(0.55f * total));                  // (Z+1)/(2Z)
    }
}

// ---- Fallback (strided) path ----

__global__ __launch_bounds__(320) void k_gather(const float* __restrict__ rv,
                                                const int* __restrict__ wid,
                                                float* __restrict__ normed) {
    int b = blockIdx.x;
    int tid = threadIdx.x;
    __shared__ int ids[NGc];
    __shared__ float wpart[5];
    __shared__ float s_inv;
    if (tid < NGc) ids[tid] = wid[b * NGc + tid];
    __syncthreads();
    float g = 0.f;
    if (tid < WE) {
        const float* row = rv + (size_t)tid * VV;
        #pragma unroll
        for (int ng = 0; ng < NGc; ++ng) g += row[ids[ng]];
        g *= 0.1f;
    }
    float r = wave_reduce(g * g);
    int lane = tid & 63, wv = tid >> 6;
    if (lane == 0) wpart[wv] = r;
    __syncthreads();
    if (tid == 0) {
        float s = wpart[0] + wpart[1] + wpart[2] + wpart[3] + wpart[4];
        s_inv = 1.0f / sqrtf(s);
    }
    __syncthreads();
    if (tid < WE) normed[(size_t)b * WE + tid] = g * s_inv;
}

__global__ __launch_bounds__(256) void k_loss(const float* __restrict__ tpre,
                                              const float* __restrict__ meanf,
                                              const float* __restrict__ scalef,
                                              const float* __restrict__ beta,
                                              const float* __restrict__ rd,
                                              const int* __restrict__ doc_ids,
                                              const int* __restrict__ neg_ids,
                                              double* __restrict__ acc) {
    int b = blockIdx.x;
    int de = threadIdx.x;
    float t = tpre[(size_t)b * DEp + de];
    float tv = (t - meanf[de]) * scalef[de] + beta[de];
    tv = fminf(1.f, fmaxf(-1.f, tv));
    const float* rdrow = rd + (size_t)de * DDim;
    __shared__ int ids[11];
    if (de == 0) ids[0] = doc_ids[b];
    if (de >= 1 && de < 11) ids[de] = neg_ids[b * NGc + de - 1];
    __syncthreads();
    float prod[11];
    #pragma unroll
    for (int j = 0; j < 11; ++j) prod[j] = tv * rdrow[ids[j]];
    __shared__ float part[11][4];
    int lane = de & 63, wv = de >> 6;
    #pragma unroll
    for (int j = 0; j < 11; ++j) {
        float r = wave_reduce(prod[j]);
        if (lane == 0) part[j][wv] = r;
    }
    __syncthreads();
    if (de == 0) {
        float x0 = part[0][0] + part[0][1] + part[0][2] + part[0][3];
        float total = 10.f * fminf(logsigf(x0), -1.0005003e-3f);
        #pragma unroll
        for (int j = 1; j < 11; ++j) {
            float xj = part[j][0] + part[j][1] + part[j][2] + part[j][3];
            total += fmaxf(logsigf(-xj), -4.6051702f);
        }
        atomicAdd(acc, (double)(0.55f * total));
    }
}

// ---- Shared middle kernels ----

// t_pre[b][de] = sum_w proj[de][w] * normed[b][w].  64x64 tiles, 4x4 micro-tile.
__global__ __launch_bounds__(256) void k_gemm(const float* __restrict__ proj,
                                              const float* __restrict__ normed,
                                              float* __restrict__ tpre) {
    __shared__ float As[64 * 33];
    __shared__ float Bs[64 * 33];
    int tid = threadIdx.x;
    int tx = tid & 15, ty = tid >> 4;
    int de0 = blockIdx.y * 64;
    int b0  = blockIdx.x * 64;
    float acc[4][4] = {};
    int f = tid & 7, r0 = tid >> 3;
    for (int kt = 0; kt < 10; ++kt) {
        int k0 = kt * 32;
        __syncthreads();
        for (int rr = r0; rr < 64; rr += 32) {
            int k = k0 + f * 4;
            float4 va = make_float4(0.f, 0.f, 0.f, 0.f);
            float4 vb = make_float4(0.f, 0.f, 0.f, 0.f);
            if (k + 3 < WE) {
                va = *(const float4*)(proj + (size_t)(de0 + rr) * WE + k);
                vb = *(const float4*)(normed + (size_t)(b0 + rr) * WE + k);
            }
            float* ap = &As[rr * 33 + f * 4];
            ap[0] = va.x; ap[1] = va.y; ap[2] = va.z; ap[3] = va.w;
            float* bp = &Bs[rr * 33 + f * 4];
            bp[0] = vb.x; bp[1] = vb.y; bp[2] = vb.z; bp[3] = vb.w;
        }
        __syncthreads();
        #pragma unroll
        for (int k = 0; k < 32; ++k) {
            float a[4], bv[4];
            #pragma unroll
            for (int i = 0; i < 4; ++i) a[i] = As[(tx * 4 + i) * 33 + k];
            #pragma unroll
            for (int j = 0; j < 4; ++j) bv[j] = Bs[(ty * 4 + j) * 33 + k];
            #pragma unroll
            for (int j = 0; j < 4; ++j)
                #pragma unroll
                for (int i = 0; i < 4; ++i) acc[j][i] += a[i] * bv[j];
        }
    }
    #pragma unroll
    for (int jb = 0; jb < 4; ++jb) {
        int b = b0 + ty * 4 + jb;
        float4 v = make_float4(acc[jb][0], acc[jb][1], acc[jb][2], acc[jb][3]);
        *(float4*)(tpre + (size_t)b * DEp + de0 + tx * 4) = v;
    }
}

__global__ __launch_bounds__(256) void k_stats1(const float* __restrict__ tpre,
                                                double* __restrict__ rowsum,
                                                double* __restrict__ rowsq) {
    int de = threadIdx.x;
    int c0 = blockIdx.x * 64;
    float s = 0.f, ss = 0.f;
    for (int i = 0; i < 64; ++i) {
        float v = tpre[(size_t)(c0 + i) * DEp + de];
        s += v; ss += v * v;
    }
    atomicAdd(&rowsum[de], (double)s);
    atomicAdd(&rowsq[de], (double)ss);
}

__global__ void k_stats2(const double* __restrict__ rowsum, const double* __restrict__ rowsq,
                         float* __restrict__ meanf, float* __restrict__ scalef) {
    int de = threadIdx.x;
    double s = rowsum[de], ss = rowsq[de];
    double mean = s / (double)BB;
    double var = (ss - s * s / (double)BB) / (double)(BB - 1);
    double stdv = sqrt(var);
    meanf[de]  = (float)mean;
    scalef[de] = (float)(1.0 / sqrt(stdv));   // reference divides by sqrt(std) = var^0.25
}

__global__ __launch_bounds__(256) void k_reg(const float4* __restrict__ p, int n4,
                                             double* __restrict__ acc) {
    int idx = blockIdx.x * blockDim.x + threadIdx.x;
    int stride = gridDim.x * blockDim.x;
    float s = 0.f;
    for (int i = idx; i < n4; i += stride) {
        float4 v = p[i];
        s += v.x * v.x + v.y * v.y + v.z * v.z + v.w * v.w;
    }
    float r = wave_reduce(s);
    __shared__ float part[4];
    int lane = threadIdx.x & 63, wv = threadIdx.x >> 6;
    if (lane == 0) part[wv] = r;
    __syncthreads();
    if (threadIdx.x == 0)
        atomicAdd(acc, (double)(part[0] + part[1] + part[2] + part[3]));
}

__global__ void k_final(const double* __restrict__ accs, float* __restrict__ out) {
    double loss = accs[0] / (double)BB + (0.01 / (2.0 * (double)BB)) * (accs[1] + accs[2]);
    out[0] = (float)loss;
}

extern "C" void kernel_launch(void* const* d_in, const int* in_sizes, int n_in,
                              void* d_out, int out_size, void* d_ws, size_t ws_size,
                              hipStream_t stream) {
    const float* rv   = (const float*)d_in[0];
    const float* rd   = (const float*)d_in[1];
    const float* proj = (const float*)d_in[2];
    const float* beta = (const float*)d_in[3];
    const int* wid    = (const int*)d_in[4];
    const int* doc    = (const int*)d_in[5];
    const int* neg    = (const int*)d_in[6];
    float* out = (float*)d_out;
    char* ws = (char*)d_ws;

    // Big-path layout: rdT (102.4 MB) at 0; rvT (60.8 MB padded) aliases it
    // (dead before rdT written).
    const size_t off_big    = 0;
    const size_t off_normed = 102400000;
    const size_t off_tpre   = off_normed + 4915200;
    const size_t off_small  = off_tpre + 4194304;
    const size_t need = off_small + 1024 + 1024 + 2048 + 2048 + 24;

    if (ws_size >= need) {
        float*  rvT    = (float*)(ws + off_big);
        float*  rdT    = (float*)(ws + off_big);
        float*  normed = (float*)(ws + off_normed);
        float*  tpre   = (float*)(ws + off_tpre);
        float*  meanf  = (float*)(ws + off_small);
        float*  scalef = (float*)(ws + off_small + 1024);
        double* rowsum = (double*)(ws + off_small + 2048);
        double* rowsq  = (double*)(ws + off_small + 4096);
        double* accs   = (double*)(ws + off_small + 6144);

        k_init<<<3, 256, 0, stream>>>(rowsum, 515);
        k_trv<<<782, 256, 0, stream>>>(rv, rvT);
        k_gather2<<<BB, 320, 0, stream>>>(rvT, wid, normed);
        k_gemm<<<dim3(64, 4), 256, 0, stream>>>(proj, normed, tpre);
        k_stats1<<<64, 256, 0, stream>>>(tpre, rowsum, rowsq);
        k_stats2<<<1, 256, 0, stream>>>(rowsum, rowsq, meanf, scalef);
        k_trd<<<1563, 256, 0, stream>>>(rd, rdT, accs + 1);
        k_loss2<<<BB, 256, 0, stream>>>(tpre, meanf, scalef, beta, rdT, doc, neg, accs);
        k_reg<<<75, 256, 0, stream>>>((const float4*)proj, 19200, accs + 2);
        k_final<<<1, 1, 0, stream>>>(accs, out);
    } else {
        // Fallback: strided path (9.2 MB workspace)
        float*  normed = (float*)(ws);
        float*  tpre   = (float*)(ws + 4915200);
        float*  meanf  = (float*)(ws + 9109504);
        float*  scalef = (float*)(ws + 9110528);
        double* rowsum = (double*)(ws + 9111552);
        double* rowsq  = (double*)(ws + 9113600);
        double* accs   = (double*)(ws + 9115648);

        k_init<<<3, 256, 0, stream>>>(rowsum, 515);
        k_gather<<<BB, 320, 0, stream>>>(rv, wid, normed);
        k_gemm<<<dim3(64, 4), 256, 0, stream>>>(proj, normed, tpre);
        k_stats1<<<64, 256, 0, stream>>>(tpre, rowsum, rowsq);
        k_stats2<<<1, 256, 0, stream>>>(rowsum, rowsq, meanf, scalef);
        k_loss<<<BB, 256, 0, stream>>>(tpre, meanf, scalef, beta, rd, doc, neg, accs);
        k_reg<<<1024, 256, 0, stream>>>((const float4*)rd, 6400000, accs + 1);
        k_reg<<<75, 256, 0, stream>>>((const float4*)proj, 19200, accs + 2);
        k_final<<<1, 1, 0, stream>>>(accs, out);
    }
}

// Round 2
// 301.080 us; speedup vs baseline: 1.2915x; 1.1604x over previous
//
#include <hip/hip_runtime.h>
#include <math.h>

#define WE 300
#define DEp 256
#define VV 50000
#define DDim 100000
#define BB 4096
#define NGc 10
#define RVT_STRIDE 304   // padded row stride (floats) for rvT, 16B-aligned

__device__ __forceinline__ float wave_reduce(float v) {
    #pragma unroll
    for (int o = 32; o > 0; o >>= 1) v += __shfl_down(v, o, 64);
    return v;
}

// butterfly: all 64 lanes end with the total
__device__ __forceinline__ float wave_allreduce(float v) {
    #pragma unroll
    for (int o = 32; o > 0; o >>= 1) v += __shfl_xor(v, o, 64);
    return v;
}

// log(sigmoid(x)), numerically stable
__device__ __forceinline__ float logsigf(float x) {
    return (x >= 0.f) ? -log1pf(expf(-x)) : x - log1pf(expf(x));
}

__global__ void k_init(double* p, int n) {
    int i = blockIdx.x * blockDim.x + threadIdx.x;
    if (i < n) p[i] = 0.0;
}

// ---- rd transpose: 256 x 100000 -> 100000 x 256, fused sum(rd*rd). ----
// One block per 64-column tile, covering ALL 256 rows. Each block's output
// region is a single contiguous 64 KB span -> perfectly sequential stores.
__global__ __launch_bounds__(256) void k_trd(const float* __restrict__ in,
                                             float* __restrict__ out,
                                             double* __restrict__ reg_acc) {
    __shared__ float4 tile[64 * 64];
    const int N = DDim;
    int n0 = blockIdx.x * 64;
    int t = threadIdx.x;
    float ss = 0.f;
    #pragma unroll
    for (int i = 0; i < 4; ++i) {
        int flat = i * 256 + t;
        int qn = flat & 15;        // n-quad within tile (0..15)
        int qm = flat >> 4;        // m-quad (0..63)
        int n = n0 + qn * 4;
        float4 v0, v1, v2, v3;
        if (n < N) {               // N%4==0 so n<N => n+3<N
            const float* p = in + (size_t)(qm * 4) * N + n;
            v0 = *(const float4*)(p);
            v1 = *(const float4*)(p + N);
            v2 = *(const float4*)(p + 2 * (size_t)N);
            v3 = *(const float4*)(p + 3 * (size_t)N);
        } else {
            v0 = v1 = v2 = v3 = make_float4(0.f, 0.f, 0.f, 0.f);
        }
        ss += v0.x * v0.x + v0.y * v0.y + v0.z * v0.z + v0.w * v0.w;
        ss += v1.x * v1.x + v1.y * v1.y + v1.z * v1.z + v1.w * v1.w;
        ss += v2.x * v2.x + v2.y * v2.y + v2.z * v2.z + v2.w * v2.w;
        ss += v3.x * v3.x + v3.y * v3.y + v3.z * v3.z + v3.w * v3.w;
        int nl0 = qn * 4;
        tile[(nl0 + 0) * 64 + (qm ^ (nl0 + 0))] = make_float4(v0.x, v1.x, v2.x, v3.x);
        tile[(nl0 + 1) * 64 + (qm ^ (nl0 + 1))] = make_float4(v0.y, v1.y, v2.y, v3.y);
        tile[(nl0 + 2) * 64 + (qm ^ (nl0 + 2))] = make_float4(v0.z, v1.z, v2.z, v3.z);
        tile[(nl0 + 3) * 64 + (qm ^ (nl0 + 3))] = make_float4(v0.w, v1.w, v2.w, v3.w);
    }
    __syncthreads();
    size_t base = (size_t)n0 * DEp;   // floats
    #pragma unroll
    for (int i = 0; i < 16; ++i) {
        int j = i * 256 + t;          // float4 index within block's out region
        int nl = j >> 6;              // wave-uniform
        if (n0 + nl < N)
            *(float4*)(out + base + (size_t)j * 4) = tile[nl * 64 + ((j & 63) ^ nl)];
    }
    float r = wave_reduce(ss);
    __shared__ float part[4];
    int lane = t & 63, wv = t >> 6;
    if (lane == 0) part[wv] = r;
    __syncthreads();
    if (t == 0)
        atomicAdd(reg_acc, (double)(part[0] + part[1] + part[2] + part[3]));
}

// ---- rv transpose: 300 x 50000 -> 50000 x 304 (padded rows). ----
__global__ __launch_bounds__(256) void k_trv(const float* __restrict__ in,
                                             float* __restrict__ out) {
    __shared__ float4 tile[64 * 80];
    const int N = VV;
    int n0 = blockIdx.x * 64;
    int t = threadIdx.x;
    #pragma unroll
    for (int i = 0; i < 5; ++i) {
        int flat = i * 256 + t;
        if (flat < 1200) {            // 75 m-quads * 16 n-quads
            int qn = flat & 15;
            int qm = flat >> 4;       // 0..74
            int n = n0 + qn * 4;
            float4 v0, v1, v2, v3;
            if (n < N) {
                const float* p = in + (size_t)(qm * 4) * N + n;
                v0 = *(const float4*)(p);
                v1 = *(const float4*)(p + N);
                v2 = *(const float4*)(p + 2 * (size_t)N);
                v3 = *(const float4*)(p + 3 * (size_t)N);
            } else {
                v0 = v1 = v2 = v3 = make_float4(0.f, 0.f, 0.f, 0.f);
            }
            int sw = qm ^ qn;
            tile[(qn * 4 + 0) * 80 + sw] = make_float4(v0.x, v1.x, v2.x, v3.x);
            tile[(qn * 4 + 1) * 80 + sw] = make_float4(v0.y, v1.y, v2.y, v3.y);
            tile[(qn * 4 + 2) * 80 + sw] = make_float4(v0.z, v1.z, v2.z, v3.z);
            tile[(qn * 4 + 3) * 80 + sw] = make_float4(v0.w, v1.w, v2.w, v3.w);
        }
    }
    __syncthreads();
    size_t base = (size_t)n0 * (RVT_STRIDE / 4);   // float4 units
    float4* out4 = (float4*)out;
    for (int i = 0; i < 19; ++i) {    // 64 * 76 = 4864 float4 per block
        int j = i * 256 + t;
        int nl = j / 76;
        int m4 = j - nl * 76;         // 75 == pad column: writes LDS junk, never read
        if (n0 + nl < N)
            out4[base + j] = tile[nl * 80 + (m4 ^ (nl >> 2))];
    }
}

// ---- Coalesced path (uses rvT / rdT) ----

// One WAVE per b: lane l owns de = 4l..4l+3 (float4), lanes 0..10 cover the
// 256..299 tail. Butterfly reduce, no LDS, no barriers.
__global__ __launch_bounds__(256) void k_gather2(const float* __restrict__ rvT,
                                                 const int* __restrict__ wid,
                                                 float* __restrict__ normed) {
    int wv = threadIdx.x >> 6, lane = threadIdx.x & 63;
    int b = blockIdx.x * 4 + wv;
    int id = 0;
    if (lane < NGc) id = wid[b * NGc + lane];
    float4 a  = make_float4(0.f, 0.f, 0.f, 0.f);
    float4 a2 = make_float4(0.f, 0.f, 0.f, 0.f);
    #pragma unroll
    for (int ng = 0; ng < NGc; ++ng) {
        int rid = __shfl(id, ng, 64);
        const float* row = rvT + (size_t)rid * RVT_STRIDE;
        float4 v = *(const float4*)(row + lane * 4);
        a.x += v.x; a.y += v.y; a.z += v.z; a.w += v.w;
        if (lane < 11) {
            float4 w = *(const float4*)(row + 256 + lane * 4);
            a2.x += w.x; a2.y += w.y; a2.z += w.z; a2.w += w.w;
        }
    }
    a.x *= 0.1f; a.y *= 0.1f; a.z *= 0.1f; a.w *= 0.1f;
    a2.x *= 0.1f; a2.y *= 0.1f; a2.z *= 0.1f; a2.w *= 0.1f;
    float ss = a.x * a.x + a.y * a.y + a.z * a.z + a.w * a.w
             + a2.x * a2.x + a2.y * a2.y + a2.z * a2.z + a2.w * a2.w;
    float s = wave_allreduce(ss);
    float s_inv = 1.0f / sqrtf(s);
    float* orow = normed + (size_t)b * WE;
    *(float4*)(orow + lane * 4) =
        make_float4(a.x * s_inv, a.y * s_inv, a.z * s_inv, a.w * s_inv);
    if (lane < 11)
        *(float4*)(orow + 256 + lane * 4) =
            make_float4(a2.x * s_inv, a2.y * s_inv, a2.z * s_inv, a2.w * s_inv);
}

// One WAVE per b: float4 loads, 11 independent gathers in flight, butterfly
// reduces, sums distributed to lanes 0..10 -> parallel logsig, 1 atomic/block.
__global__ __launch_bounds__(256) void k_loss2(const float* __restrict__ tpre,
                                               const float* __restrict__ meanf,
                                               const float* __restrict__ scalef,
                                               const float* __restrict__ beta,
                                               const float* __restrict__ rdT,
                                               const int* __restrict__ doc_ids,
                                               const int* __restrict__ neg_ids,
                                               double* __restrict__ acc) {
    int wv = threadIdx.x >> 6, lane = threadIdx.x & 63;
    int b = blockIdx.x * 4 + wv;

    float4 t4  = *(const float4*)(tpre + (size_t)b * DEp + lane * 4);
    float4 m4  = *(const float4*)(meanf + lane * 4);
    float4 sc4 = *(const float4*)(scalef + lane * 4);
    float4 be4 = *(const float4*)(beta + lane * 4);
    float tv0 = fminf(1.f, fmaxf(-1.f, (t4.x - m4.x) * sc4.x + be4.x));
    float tv1 = fminf(1.f, fmaxf(-1.f, (t4.y - m4.y) * sc4.y + be4.y));
    float tv2 = fminf(1.f, fmaxf(-1.f, (t4.z - m4.z) * sc4.z + be4.z));
    float tv3 = fminf(1.f, fmaxf(-1.f, (t4.w - m4.w) * sc4.w + be4.w));

    int id = 0;
    if (lane == 0) id = doc_ids[b];
    else if (lane < 11) id = neg_ids[b * NGc + lane - 1];

    float xv = 0.f;
    #pragma unroll
    for (int j = 0; j < 11; ++j) {
        int rid = __shfl(id, j, 64);
        float4 r4 = *(const float4*)(rdT + (size_t)rid * DEp + lane * 4);
        float p = tv0 * r4.x + tv1 * r4.y + tv2 * r4.z + tv3 * r4.w;
        p = wave_allreduce(p);
        if (lane == j) xv = p;
    }
    float contrib = 0.f;
    if (lane == 0)      contrib = 10.f * fminf(logsigf(xv), -1.0005003e-3f);
    else if (lane < 11) contrib = fmaxf(logsigf(-xv), -4.6051702f);
    #pragma unroll
    for (int o = 8; o > 0; o >>= 1) contrib += __shfl_down(contrib, o, 16);

    __shared__ float bp[4];
    if (lane == 0) bp[wv] = contrib;
    __syncthreads();
    if (threadIdx.x == 0)
        atomicAdd(acc, (double)(0.55f * (bp[0] + bp[1] + bp[2] + bp[3])));
}

// ---- Fallback (strided) path ----

__global__ __launch_bounds__(320) void k_gather(const float* __restrict__ rv,
                                                const int* __restrict__ wid,
                                                float* __restrict__ normed) {
    int b = blockIdx.x;
    int tid = threadIdx.x;
    __shared__ int ids[NGc];
    __shared__ float wpart[5];
    __shared__ float s_inv;
    if (tid < NGc) ids[tid] = wid[b * NGc + tid];
    __syncthreads();
    float g = 0.f;
    if (tid < WE) {
        const float* row = rv + (size_t)tid * VV;
        #pragma unroll
        for (int ng = 0; ng < NGc; ++ng) g += row[ids[ng]];
        g *= 0.1f;
    }
    float r = wave_reduce(g * g);
    int lane = tid & 63, wv = tid >> 6;
    if (lane == 0) wpart[wv] = r;
    __syncthreads();
    if (tid == 0) {
        float s = wpart[0] + wpart[1] + wpart[2] + wpart[3] + wpart[4];
        s_inv = 1.0f / sqrtf(s);
    }
    __syncthreads();
    if (tid < WE) normed[(size_t)b * WE + tid] = g * s_inv;
}

__global__ __launch_bounds__(256) void k_loss(const float* __restrict__ tpre,
                                              const float* __restrict__ meanf,
                                              const float* __restrict__ scalef,
                                              const float* __restrict__ beta,
                                              const float* __restrict__ rd,
                                              const int* __restrict__ doc_ids,
                                              const int* __restrict__ neg_ids,
                                              double* __restrict__ acc) {
    int b = blockIdx.x;
    int de = threadIdx.x;
    float t = tpre[(size_t)b * DEp + de];
    float tv = (t - meanf[de]) * scalef[de] + beta[de];
    tv = fminf(1.f, fmaxf(-1.f, tv));
    const float* rdrow = rd + (size_t)de * DDim;
    __shared__ int ids[11];
    if (de == 0) ids[0] = doc_ids[b];
    if (de >= 1 && de < 11) ids[de] = neg_ids[b * NGc + de - 1];
    __syncthreads();
    float prod[11];
    #pragma unroll
    for (int j = 0; j < 11; ++j) prod[j] = tv * rdrow[ids[j]];
    __shared__ float part[11][4];
    int lane = de & 63, wv = de >> 6;
    #pragma unroll
    for (int j = 0; j < 11; ++j) {
        float r = wave_reduce(prod[j]);
        if (lane == 0) part[j][wv] = r;
    }
    __syncthreads();
    if (de == 0) {
        float x0 = part[0][0] + part[0][1] + part[0][2] + part[0][3];
        float total = 10.f * fminf(logsigf(x0), -1.0005003e-3f);
        #pragma unroll
        for (int j = 1; j < 11; ++j) {
            float xj = part[j][0] + part[j][1] + part[j][2] + part[j][3];
            total += fmaxf(logsigf(-xj), -4.6051702f);
        }
        atomicAdd(acc, (double)(0.55f * total));
    }
}

// ---- Shared middle kernels ----

__global__ __launch_bounds__(256) void k_gemm(const float* __restrict__ proj,
                                              const float* __restrict__ normed,
                                              float* __restrict__ tpre) {
    __shared__ float As[64 * 33];
    __shared__ float Bs[64 * 33];
    int tid = threadIdx.x;
    int tx = tid & 15, ty = tid >> 4;
    int de0 = blockIdx.y * 64;
    int b0  = blockIdx.x * 64;
    float acc[4][4] = {};
    int f = tid & 7, r0 = tid >> 3;
    for (int kt = 0; kt < 10; ++kt) {
        int k0 = kt * 32;
        __syncthreads();
        for (int rr = r0; rr < 64; rr += 32) {
            int k = k0 + f * 4;
            float4 va = make_float4(0.f, 0.f, 0.f, 0.f);
            float4 vb = make_float4(0.f, 0.f, 0.f, 0.f);
            if (k + 3 < WE) {
                va = *(const float4*)(proj + (size_t)(de0 + rr) * WE + k);
                vb = *(const float4*)(normed + (size_t)(b0 + rr) * WE + k);
            }
            float* ap = &As[rr * 33 + f * 4];
            ap[0] = va.x; ap[1] = va.y; ap[2] = va.z; ap[3] = va.w;
            float* bp = &Bs[rr * 33 + f * 4];
            bp[0] = vb.x; bp[1] = vb.y; bp[2] = vb.z; bp[3] = vb.w;
        }
        __syncthreads();
        #pragma unroll
        for (int k = 0; k < 32; ++k) {
            float a[4], bv[4];
            #pragma unroll
            for (int i = 0; i < 4; ++i) a[i] = As[(tx * 4 + i) * 33 + k];
            #pragma unroll
            for (int j = 0; j < 4; ++j) bv[j] = Bs[(ty * 4 + j) * 33 + k];
            #pragma unroll
            for (int j = 0; j < 4; ++j)
                #pragma unroll
                for (int i = 0; i < 4; ++i) acc[j][i] += a[i] * bv[j];
        }
    }
    #pragma unroll
    for (int jb = 0; jb < 4; ++jb) {
        int b = b0 + ty * 4 + jb;
        float4 v = make_float4(acc[jb][0], acc[jb][1], acc[jb][2], acc[jb][3]);
        *(float4*)(tpre + (size_t)b * DEp + de0 + tx * 4) = v;
    }
}

__global__ __launch_bounds__(256) void k_stats1(const float* __restrict__ tpre,
                                                double* __restrict__ rowsum,
                                                double* __restrict__ rowsq) {
    int de = threadIdx.x;
    int c0 = blockIdx.x * 64;
    float s = 0.f, ss = 0.f;
    for (int i = 0; i < 64; ++i) {
        float v = tpre[(size_t)(c0 + i) * DEp + de];
        s += v; ss += v * v;
    }
    atomicAdd(&rowsum[de], (double)s);
    atomicAdd(&rowsq[de], (double)ss);
}

__global__ void k_stats2(const double* __restrict__ rowsum, const double* __restrict__ rowsq,
                         float* __restrict__ meanf, float* __restrict__ scalef) {
    int de = threadIdx.x;
    double s = rowsum[de], ss = rowsq[de];
    double mean = s / (double)BB;
    double var = (ss - s * s / (double)BB) / (double)(BB - 1);
    double stdv = sqrt(var);
    meanf[de]  = (float)mean;
    scalef[de] = (float)(1.0 / sqrt(stdv));   // reference divides by sqrt(std) = var^0.25
}

__global__ __launch_bounds__(256) void k_reg(const float4* __restrict__ p, int n4,
                                             double* __restrict__ acc) {
    int idx = blockIdx.x * blockDim.x + threadIdx.x;
    int stride = gridDim.x * blockDim.x;
    float s = 0.f;
    for (int i = idx; i < n4; i += stride) {
        float4 v = p[i];
        s += v.x * v.x + v.y * v.y + v.z * v.z + v.w * v.w;
    }
    float r = wave_reduce(s);
    __shared__ float part[4];
    int lane = threadIdx.x & 63, wv = threadIdx.x >> 6;
    if (lane == 0) part[wv] = r;
    __syncthreads();
    if (threadIdx.x == 0)
        atomicAdd(acc, (double)(part[0] + part[1] + part[2] + part[3]));
}

__global__ void k_final(const double* __restrict__ accs, float* __restrict__ out) {
    double loss = accs[0] / (double)BB + (0.01 / (2.0 * (double)BB)) * (accs[1] + accs[2]);
    out[0] = (float)loss;
}

extern "C" void kernel_launch(void* const* d_in, const int* in_sizes, int n_in,
                              void* d_out, int out_size, void* d_ws, size_t ws_size,
                              hipStream_t stream) {
    const float* rv   = (const float*)d_in[0];
    const float* rd   = (const float*)d_in[1];
    const float* proj = (const float*)d_in[2];
    const float* beta = (const float*)d_in[3];
    const int* wid    = (const int*)d_in[4];
    const int* doc    = (const int*)d_in[5];
    const int* neg    = (const int*)d_in[6];
    float* out = (float*)d_out;
    char* ws = (char*)d_ws;

    // Big-path layout: rdT (102.4 MB) at 0; rvT (60.8 MB padded) aliases it
    // (dead before rdT written).
    const size_t off_big    = 0;
    const size_t off_normed = 102400000;
    const size_t off_tpre   = off_normed + 4915200;
    const size_t off_small  = off_tpre + 4194304;
    const size_t need = off_small + 1024 + 1024 + 2048 + 2048 + 24;

    if (ws_size >= need) {
        float*  rvT    = (float*)(ws + off_big);
        float*  rdT    = (float*)(ws + off_big);
        float*  normed = (float*)(ws + off_normed);
        float*  tpre   = (float*)(ws + off_tpre);
        float*  meanf  = (float*)(ws + off_small);
        float*  scalef = (float*)(ws + off_small + 1024);
        double* rowsum = (double*)(ws + off_small + 2048);
        double* rowsq  = (double*)(ws + off_small + 4096);
        double* accs   = (double*)(ws + off_small + 6144);

        k_init<<<3, 256, 0, stream>>>(rowsum, 515);
        k_trv<<<782, 256, 0, stream>>>(rv, rvT);
        k_gather2<<<BB / 4, 256, 0, stream>>>(rvT, wid, normed);
        k_gemm<<<dim3(64, 4), 256, 0, stream>>>(proj, normed, tpre);
        k_stats1<<<64, 256, 0, stream>>>(tpre, rowsum, rowsq);
        k_stats2<<<1, 256, 0, stream>>>(rowsum, rowsq, meanf, scalef);
        k_trd<<<1563, 256, 0, stream>>>(rd, rdT, accs + 1);
        k_loss2<<<BB / 4, 256, 0, stream>>>(tpre, meanf, scalef, beta, rdT, doc, neg, accs);
        k_reg<<<75, 256, 0, stream>>>((const float4*)proj, 19200, accs + 2);
        k_final<<<1, 1, 0, stream>>>(accs, out);
    } else {
        // Fallback: strided path (9.2 MB workspace)
        float*  normed = (float*)(ws);
        float*  tpre   = (float*)(ws + 4915200);
        float*  meanf  = (float*)(ws + 9109504);
        float*  scalef = (float*)(ws + 9110528);
        double* rowsum = (double*)(ws + 9111552);
        double* rowsq  = (double*)(ws + 9113600);
        double* accs   = (double*)(ws + 9115648);

        k_init<<<3, 256, 0, stream>>>(rowsum, 515);
        k_gather<<<BB, 320, 0, stream>>>(rv, wid, normed);
        k_gemm<<<dim3(64, 4), 256, 0, stream>>>(proj, normed, tpre);
        k_stats1<<<64, 256, 0, stream>>>(tpre, rowsum, rowsq);
        k_stats2<<<1, 256, 0, stream>>>(rowsum, rowsq, meanf, scalef);
        k_loss<<<BB, 256, 0, stream>>>(tpre, meanf, scalef, beta, rd, doc, neg, accs);
        k_reg<<<1024, 256, 0, stream>>>((const float4*)rd, 6400000, accs + 1);
        k_reg<<<75, 256, 0, stream>>>((const float4*)proj, 19200, accs + 2);
        k_final<<<1, 1, 0, stream>>>(accs, out);
    }
}

// Round 3
// 295.745 us; speedup vs baseline: 1.3148x; 1.0180x over previous
//
#include <hip/hip_runtime.h>
#include <math.h>

#define WE 300
#define DEp 256
#define VV 50000
#define DDim 100000
#define BB 4096
#define NGc 10
#define RVT_STRIDE 304   // padded row stride (floats) for rvT, 16B-aligned

__device__ __forceinline__ float wave_reduce(float v) {
    #pragma unroll
    for (int o = 32; o > 0; o >>= 1) v += __shfl_down(v, o, 64);
    return v;
}

// butterfly: all 64 lanes end with the total
__device__ __forceinline__ float wave_allreduce(float v) {
    #pragma unroll
    for (int o = 32; o > 0; o >>= 1) v += __shfl_xor(v, o, 64);
    return v;
}

// log(sigmoid(x)), numerically stable
__device__ __forceinline__ float logsigf(float x) {
    return (x >= 0.f) ? -log1pf(expf(-x)) : x - log1pf(expf(x));
}

__global__ void k_init(double* p, int n) {
    int i = blockIdx.x * blockDim.x + threadIdx.x;
    if (i < n) p[i] = 0.0;
}

// ---- rd transpose: 256 x 100000 -> 100000 x 256, fused sum(rd*rd). ----
// 32-column tiles: LDS 32KB -> 5 blocks/CU (62% occupancy cap) so the
// load phase of some blocks overlaps the store phase of others.
// Block writes one contiguous 32KB span; reads 256 rows x 128B.
__global__ __launch_bounds__(256) void k_trd(const float* __restrict__ in,
                                             float* __restrict__ out,
                                             double* __restrict__ reg_acc) {
    __shared__ float4 tile[32 * 64];
    const int N = DDim;
    int n0 = blockIdx.x * 32;       // grid 3125, exact
    int t = threadIdx.x;
    float ss = 0.f;
    #pragma unroll
    for (int i = 0; i < 2; ++i) {
        int flat = i * 256 + t;     // 512 tasks: 8 n-quads x 64 m-quads
        int qn = flat & 7;
        int qm = flat >> 3;         // 0..63
        int n = n0 + qn * 4;
        const float* p = in + (size_t)(qm * 4) * N + n;
        float4 v0 = *(const float4*)(p);
        float4 v1 = *(const float4*)(p + N);
        float4 v2 = *(const float4*)(p + 2 * (size_t)N);
        float4 v3 = *(const float4*)(p + 3 * (size_t)N);
        ss += v0.x * v0.x + v0.y * v0.y + v0.z * v0.z + v0.w * v0.w;
        ss += v1.x * v1.x + v1.y * v1.y + v1.z * v1.z + v1.w * v1.w;
        ss += v2.x * v2.x + v2.y * v2.y + v2.z * v2.z + v2.w * v2.w;
        ss += v3.x * v3.x + v3.y * v3.y + v3.z * v3.z + v3.w * v3.w;
        int r0 = qn * 4;
        tile[(r0 + 0) * 64 + (qm ^ (r0 + 0))] = make_float4(v0.x, v1.x, v2.x, v3.x);
        tile[(r0 + 1) * 64 + (qm ^ (r0 + 1))] = make_float4(v0.y, v1.y, v2.y, v3.y);
        tile[(r0 + 2) * 64 + (qm ^ (r0 + 2))] = make_float4(v0.z, v1.z, v2.z, v3.z);
        tile[(r0 + 3) * 64 + (qm ^ (r0 + 3))] = make_float4(v0.w, v1.w, v2.w, v3.w);
    }
    __syncthreads();
    size_t base = (size_t)n0 * DEp;   // floats
    #pragma unroll
    for (int i = 0; i < 8; ++i) {
        int j = i * 256 + t;          // float4 index within block's 2048-f4 region
        int nl = j >> 6;              // 0..31, wave-uniform
        int m4 = j & 63;
        *(float4*)(out + base + (size_t)j * 4) = tile[nl * 64 + (m4 ^ nl)];
    }
    float r = wave_reduce(ss);
    __shared__ float part[4];
    int lane = t & 63, wv = t >> 6;
    if (lane == 0) part[wv] = r;
    __syncthreads();
    if (t == 0)
        atomicAdd(reg_acc, (double)(part[0] + part[1] + part[2] + part[3]));
}

// ---- rv transpose: 300 x 50000 -> 50000 x 304 (padded rows). ----
// 32-column tiles: LDS 40KB -> 4 blocks/CU. Contiguous ~38KB store span.
__global__ __launch_bounds__(256) void k_trv(const float* __restrict__ in,
                                             float* __restrict__ out) {
    __shared__ float4 tile[32 * 80];
    const int N = VV;
    int n0 = blockIdx.x * 32;
    int t = threadIdx.x;
    #pragma unroll
    for (int i = 0; i < 3; ++i) {
        int flat = i * 256 + t;
        if (flat < 600) {             // 8 n-quads x 75 m-quads
            int qn = flat & 7;
            int qm = flat >> 3;       // 0..74
            int n = n0 + qn * 4;
            float4 v0, v1, v2, v3;
            if (n < N) {              // N%4==0 so n<N => n+3<N
                const float* p = in + (size_t)(qm * 4) * N + n;
                v0 = *(const float4*)(p);
                v1 = *(const float4*)(p + N);
                v2 = *(const float4*)(p + 2 * (size_t)N);
                v3 = *(const float4*)(p + 3 * (size_t)N);
            } else {
                v0 = v1 = v2 = v3 = make_float4(0.f, 0.f, 0.f, 0.f);
            }
            int r0 = qn * 4;
            tile[(r0 + 0) * 80 + (qm ^ ((r0 + 0) & 7))] = make_float4(v0.x, v1.x, v2.x, v3.x);
            tile[(r0 + 1) * 80 + (qm ^ ((r0 + 1) & 7))] = make_float4(v0.y, v1.y, v2.y, v3.y);
            tile[(r0 + 2) * 80 + (qm ^ ((r0 + 2) & 7))] = make_float4(v0.z, v1.z, v2.z, v3.z);
            tile[(r0 + 3) * 80 + (qm ^ ((r0 + 3) & 7))] = make_float4(v0.w, v1.w, v2.w, v3.w);
        }
    }
    __syncthreads();
    size_t base = (size_t)n0 * (RVT_STRIDE / 4);   // float4 units
    float4* out4 = (float4*)out;
    for (int i = 0; i < 10; ++i) {    // 32 * 76 = 2432 float4 per block
        int j = i * 256 + t;
        if (j < 2432) {
            int nl = j / 76;
            int m4 = j - nl * 76;     // 75 == pad column: LDS junk, never read back
            if (n0 + nl < N)
                out4[base + j] = tile[nl * 80 + (m4 ^ (nl & 7))];
        }
    }
}

// ---- Coalesced path (uses rvT / rdT) ----

// One WAVE per b: lane l owns de = 4l..4l+3 (float4), lanes 0..10 cover the
// 256..299 tail. Butterfly reduce, no LDS, no barriers.
__global__ __launch_bounds__(256) void k_gather2(const float* __restrict__ rvT,
                                                 const int* __restrict__ wid,
                                                 float* __restrict__ normed) {
    int wv = threadIdx.x >> 6, lane = threadIdx.x & 63;
    int b = blockIdx.x * 4 + wv;
    int id = 0;
    if (lane < NGc) id = wid[b * NGc + lane];
    float4 a  = make_float4(0.f, 0.f, 0.f, 0.f);
    float4 a2 = make_float4(0.f, 0.f, 0.f, 0.f);
    #pragma unroll
    for (int ng = 0; ng < NGc; ++ng) {
        int rid = __shfl(id, ng, 64);
        const float* row = rvT + (size_t)rid * RVT_STRIDE;
        float4 v = *(const float4*)(row + lane * 4);
        a.x += v.x; a.y += v.y; a.z += v.z; a.w += v.w;
        if (lane < 11) {
            float4 w = *(const float4*)(row + 256 + lane * 4);
            a2.x += w.x; a2.y += w.y; a2.z += w.z; a2.w += w.w;
        }
    }
    a.x *= 0.1f; a.y *= 0.1f; a.z *= 0.1f; a.w *= 0.1f;
    a2.x *= 0.1f; a2.y *= 0.1f; a2.z *= 0.1f; a2.w *= 0.1f;
    float ss = a.x * a.x + a.y * a.y + a.z * a.z + a.w * a.w
             + a2.x * a2.x + a2.y * a2.y + a2.z * a2.z + a2.w * a2.w;
    float s = wave_allreduce(ss);
    float s_inv = 1.0f / sqrtf(s);
    float* orow = normed + (size_t)b * WE;
    *(float4*)(orow + lane * 4) =
        make_float4(a.x * s_inv, a.y * s_inv, a.z * s_inv, a.w * s_inv);
    if (lane < 11)
        *(float4*)(orow + 256 + lane * 4) =
            make_float4(a2.x * s_inv, a2.y * s_inv, a2.z * s_inv, a2.w * s_inv);
}

// One WAVE per b: float4 loads, 11 independent gathers in flight, butterfly
// reduces, sums distributed to lanes 0..10 -> parallel logsig, 1 atomic/block.
__global__ __launch_bounds__(256) void k_loss2(const float* __restrict__ tpre,
                                               const float* __restrict__ meanf,
                                               const float* __restrict__ scalef,
                                               const float* __restrict__ beta,
                                               const float* __restrict__ rdT,
                                               const int* __restrict__ doc_ids,
                                               const int* __restrict__ neg_ids,
                                               double* __restrict__ acc) {
    int wv = threadIdx.x >> 6, lane = threadIdx.x & 63;
    int b = blockIdx.x * 4 + wv;

    float4 t4  = *(const float4*)(tpre + (size_t)b * DEp + lane * 4);
    float4 m4  = *(const float4*)(meanf + lane * 4);
    float4 sc4 = *(const float4*)(scalef + lane * 4);
    float4 be4 = *(const float4*)(beta + lane * 4);
    float tv0 = fminf(1.f, fmaxf(-1.f, (t4.x - m4.x) * sc4.x + be4.x));
    float tv1 = fminf(1.f, fmaxf(-1.f, (t4.y - m4.y) * sc4.y + be4.y));
    float tv2 = fminf(1.f, fmaxf(-1.f, (t4.z - m4.z) * sc4.z + be4.z));
    float tv3 = fminf(1.f, fmaxf(-1.f, (t4.w - m4.w) * sc4.w + be4.w));

    int id = 0;
    if (lane == 0) id = doc_ids[b];
    else if (lane < 11) id = neg_ids[b * NGc + lane - 1];

    float xv = 0.f;
    #pragma unroll
    for (int j = 0; j < 11; ++j) {
        int rid = __shfl(id, j, 64);
        float4 r4 = *(const float4*)(rdT + (size_t)rid * DEp + lane * 4);
        float p = tv0 * r4.x + tv1 * r4.y + tv2 * r4.z + tv3 * r4.w;
        p = wave_allreduce(p);
        if (lane == j) xv = p;
    }
    float contrib = 0.f;
    if (lane == 0)      contrib = 10.f * fminf(logsigf(xv), -1.0005003e-3f);
    else if (lane < 11) contrib = fmaxf(logsigf(-xv), -4.6051702f);
    #pragma unroll
    for (int o = 8; o > 0; o >>= 1) contrib += __shfl_down(contrib, o, 16);

    __shared__ float bp[4];
    if (lane == 0) bp[wv] = contrib;
    __syncthreads();
    if (threadIdx.x == 0)
        atomicAdd(acc, (double)(0.55f * (bp[0] + bp[1] + bp[2] + bp[3])));
}

// ---- Fallback (strided) path ----

__global__ __launch_bounds__(320) void k_gather(const float* __restrict__ rv,
                                                const int* __restrict__ wid,
                                                float* __restrict__ normed) {
    int b = blockIdx.x;
    int tid = threadIdx.x;
    __shared__ int ids[NGc];
    __shared__ float wpart[5];
    __shared__ float s_inv;
    if (tid < NGc) ids[tid] = wid[b * NGc + tid];
    __syncthreads();
    float g = 0.f;
    if (tid < WE) {
        const float* row = rv + (size_t)tid * VV;
        #pragma unroll
        for (int ng = 0; ng < NGc; ++ng) g += row[ids[ng]];
        g *= 0.1f;
    }
    float r = wave_reduce(g * g);
    int lane = tid & 63, wv = tid >> 6;
    if (lane == 0) wpart[wv] = r;
    __syncthreads();
    if (tid == 0) {
        float s = wpart[0] + wpart[1] + wpart[2] + wpart[3] + wpart[4];
        s_inv = 1.0f / sqrtf(s);
    }
    __syncthreads();
    if (tid < WE) normed[(size_t)b * WE + tid] = g * s_inv;
}

__global__ __launch_bounds__(256) void k_loss(const float* __restrict__ tpre,
                                              const float* __restrict__ meanf,
                                              const float* __restrict__ scalef,
                                              const float* __restrict__ beta,
                                              const float* __restrict__ rd,
                                              const int* __restrict__ doc_ids,
                                              const int* __restrict__ neg_ids,
                                              double* __restrict__ acc) {
    int b = blockIdx.x;
    int de = threadIdx.x;
    float t = tpre[(size_t)b * DEp + de];
    float tv = (t - meanf[de]) * scalef[de] + beta[de];
    tv = fminf(1.f, fmaxf(-1.f, tv));
    const float* rdrow = rd + (size_t)de * DDim;
    __shared__ int ids[11];
    if (de == 0) ids[0] = doc_ids[b];
    if (de >= 1 && de < 11) ids[de] = neg_ids[b * NGc + de - 1];
    __syncthreads();
    float prod[11];
    #pragma unroll
    for (int j = 0; j < 11; ++j) prod[j] = tv * rdrow[ids[j]];
    __shared__ float part[11][4];
    int lane = de & 63, wv = de >> 6;
    #pragma unroll
    for (int j = 0; j < 11; ++j) {
        float r = wave_reduce(prod[j]);
        if (lane == 0) part[j][wv] = r;
    }
    __syncthreads();
    if (de == 0) {
        float x0 = part[0][0] + part[0][1] + part[0][2] + part[0][3];
        float total = 10.f * fminf(logsigf(x0), -1.0005003e-3f);
        #pragma unroll
        for (int j = 1; j < 11; ++j) {
            float xj = part[j][0] + part[j][1] + part[j][2] + part[j][3];
            total += fmaxf(logsigf(-xj), -4.6051702f);
        }
        atomicAdd(acc, (double)(0.55f * total));
    }
}

// ---- Shared middle kernels ----

__global__ __launch_bounds__(256) void k_gemm(const float* __restrict__ proj,
                                              const float* __restrict__ normed,
                                              float* __restrict__ tpre) {
    __shared__ float As[64 * 33];
    __shared__ float Bs[64 * 33];
    int tid = threadIdx.x;
    int tx = tid & 15, ty = tid >> 4;
    int de0 = blockIdx.y * 64;
    int b0  = blockIdx.x * 64;
    float acc[4][4] = {};
    int f = tid & 7, r0 = tid >> 3;
    for (int kt = 0; kt < 10; ++kt) {
        int k0 = kt * 32;
        __syncthreads();
        for (int rr = r0; rr < 64; rr += 32) {
            int k = k0 + f * 4;
            float4 va = make_float4(0.f, 0.f, 0.f, 0.f);
            float4 vb = make_float4(0.f, 0.f, 0.f, 0.f);
            if (k + 3 < WE) {
                va = *(const float4*)(proj + (size_t)(de0 + rr) * WE + k);
                vb = *(const float4*)(normed + (size_t)(b0 + rr) * WE + k);
            }
            float* ap = &As[rr * 33 + f * 4];
            ap[0] = va.x; ap[1] = va.y; ap[2] = va.z; ap[3] = va.w;
            float* bp = &Bs[rr * 33 + f * 4];
            bp[0] = vb.x; bp[1] = vb.y; bp[2] = vb.z; bp[3] = vb.w;
        }
        __syncthreads();
        #pragma unroll
        for (int k = 0; k < 32; ++k) {
            float a[4], bv[4];
            #pragma unroll
            for (int i = 0; i < 4; ++i) a[i] = As[(tx * 4 + i) * 33 + k];
            #pragma unroll
            for (int j = 0; j < 4; ++j) bv[j] = Bs[(ty * 4 + j) * 33 + k];
            #pragma unroll
            for (int j = 0; j < 4; ++j)
                #pragma unroll
                for (int i = 0; i < 4; ++i) acc[j][i] += a[i] * bv[j];
        }
    }
    #pragma unroll
    for (int jb = 0; jb < 4; ++jb) {
        int b = b0 + ty * 4 + jb;
        float4 v = make_float4(acc[jb][0], acc[jb][1], acc[jb][2], acc[jb][3]);
        *(float4*)(tpre + (size_t)b * DEp + de0 + tx * 4) = v;
    }
}

__global__ __launch_bounds__(256) void k_stats1(const float* __restrict__ tpre,
                                                double* __restrict__ rowsum,
                                                double* __restrict__ rowsq) {
    int de = threadIdx.x;
    int c0 = blockIdx.x * 64;
    float s = 0.f, ss = 0.f;
    for (int i = 0; i < 64; ++i) {
        float v = tpre[(size_t)(c0 + i) * DEp + de];
        s += v; ss += v * v;
    }
    atomicAdd(&rowsum[de], (double)s);
    atomicAdd(&rowsq[de], (double)ss);
}

__global__ void k_stats2(const double* __restrict__ rowsum, const double* __restrict__ rowsq,
                         float* __restrict__ meanf, float* __restrict__ scalef) {
    int de = threadIdx.x;
    double s = rowsum[de], ss = rowsq[de];
    double mean = s / (double)BB;
    double var = (ss - s * s / (double)BB) / (double)(BB - 1);
    double stdv = sqrt(var);
    meanf[de]  = (float)mean;
    scalef[de] = (float)(1.0 / sqrt(stdv));   // reference divides by sqrt(std) = var^0.25
}

__global__ __launch_bounds__(256) void k_reg(const float4* __restrict__ p, int n4,
                                             double* __restrict__ acc) {
    int idx = blockIdx.x * blockDim.x + threadIdx.x;
    int stride = gridDim.x * blockDim.x;
    float s = 0.f;
    for (int i = idx; i < n4; i += stride) {
        float4 v = p[i];
        s += v.x * v.x + v.y * v.y + v.z * v.z + v.w * v.w;
    }
    float r = wave_reduce(s);
    __shared__ float part[4];
    int lane = threadIdx.x & 63, wv = threadIdx.x >> 6;
    if (lane == 0) part[wv] = r;
    __syncthreads();
    if (threadIdx.x == 0)
        atomicAdd(acc, (double)(part[0] + part[1] + part[2] + part[3]));
}

__global__ void k_final(const double* __restrict__ accs, float* __restrict__ out) {
    double loss = accs[0] / (double)BB + (0.01 / (2.0 * (double)BB)) * (accs[1] + accs[2]);
    out[0] = (float)loss;
}

extern "C" void kernel_launch(void* const* d_in, const int* in_sizes, int n_in,
                              void* d_out, int out_size, void* d_ws, size_t ws_size,
                              hipStream_t stream) {
    const float* rv   = (const float*)d_in[0];
    const float* rd   = (const float*)d_in[1];
    const float* proj = (const float*)d_in[2];
    const float* beta = (const float*)d_in[3];
    const int* wid    = (const int*)d_in[4];
    const int* doc    = (const int*)d_in[5];
    const int* neg    = (const int*)d_in[6];
    float* out = (float*)d_out;
    char* ws = (char*)d_ws;

    // Big-path layout: rdT (102.4 MB) at 0; rvT (60.8 MB padded) aliases it
    // (dead before rdT written).
    const size_t off_big    = 0;
    const size_t off_normed = 102400000;
    const size_t off_tpre   = off_normed + 4915200;
    const size_t off_small  = off_tpre + 4194304;
    const size_t need = off_small + 1024 + 1024 + 2048 + 2048 + 24;

    if (ws_size >= need) {
        float*  rvT    = (float*)(ws + off_big);
        float*  rdT    = (float*)(ws + off_big);
        float*  normed = (float*)(ws + off_normed);
        float*  tpre   = (float*)(ws + off_tpre);
        float*  meanf  = (float*)(ws + off_small);
        float*  scalef = (float*)(ws + off_small + 1024);
        double* rowsum = (double*)(ws + off_small + 2048);
        double* rowsq  = (double*)(ws + off_small + 4096);
        double* accs   = (double*)(ws + off_small + 6144);

        k_init<<<3, 256, 0, stream>>>(rowsum, 515);
        k_trv<<<1563, 256, 0, stream>>>(rv, rvT);
        k_gather2<<<BB / 4, 256, 0, stream>>>(rvT, wid, normed);
        k_gemm<<<dim3(64, 4), 256, 0, stream>>>(proj, normed, tpre);
        k_stats1<<<64, 256, 0, stream>>>(tpre, rowsum, rowsq);
        k_stats2<<<1, 256, 0, stream>>>(rowsum, rowsq, meanf, scalef);
        k_trd<<<3125, 256, 0, stream>>>(rd, rdT, accs + 1);
        k_loss2<<<BB / 4, 256, 0, stream>>>(tpre, meanf, scalef, beta, rdT, doc, neg, accs);
        k_reg<<<75, 256, 0, stream>>>((const float4*)proj, 19200, accs + 2);
        k_final<<<1, 1, 0, stream>>>(accs, out);
    } else {
        // Fallback: strided path (9.2 MB workspace)
        float*  normed = (float*)(ws);
        float*  tpre   = (float*)(ws + 4915200);
        float*  meanf  = (float*)(ws + 9109504);
        float*  scalef = (float*)(ws + 9110528);
        double* rowsum = (double*)(ws + 9111552);
        double* rowsq  = (double*)(ws + 9113600);
        double* accs   = (double*)(ws + 9115648);

        k_init<<<3, 256, 0, stream>>>(rowsum, 515);
        k_gather<<<BB, 320, 0, stream>>>(rv, wid, normed);
        k_gemm<<<dim3(64, 4), 256, 0, stream>>>(proj, normed, tpre);
        k_stats1<<<64, 256, 0, stream>>>(tpre, rowsum, rowsq);
        k_stats2<<<1, 256, 0, stream>>>(rowsum, rowsq, meanf, scalef);
        k_loss<<<BB, 256, 0, stream>>>(tpre, meanf, scalef, beta, rd, doc, neg, accs);
        k_reg<<<1024, 256, 0, stream>>>((const float4*)rd, 6400000, accs + 1);
        k_reg<<<75, 256, 0, stream>>>((const float4*)proj, 19200, accs + 2);
        k_final<<<1, 1, 0, stream>>>(accs, out);
    }
}